// Round 1
// 734.525 us; speedup vs baseline: 1.2961x; 1.2961x over previous
//
#include <hip/hip_runtime.h>

// GRUAdder: B=1048576 sequences, T=4, I=2, H=16.
// v2: two batch elements per thread (2x ILP per wave), t-loop ROLLED
// (#pragma unroll 1) so the hot body fits L1 I$, launch_bounds(256,4)
// to allow ~128 VGPRs of scheduling freedom (baseline was squeezed to 44).

constexpr long long Bn = 1048576;
constexpr int Hn = 16;

__device__ __forceinline__ float sigm_f(float x) {
    // 1 / (1 + e^-x)
    return __builtin_amdgcn_rcpf(1.0f + __expf(-x));
}
__device__ __forceinline__ float tanh_f(float x) {
    // tanh(x) = 1 - 2/(e^{2x}+1)
    return 1.0f - 2.0f * __builtin_amdgcn_rcpf(1.0f + __expf(2.0f * x));
}

// One GRU step with h == 0 (t = 0): gh == b_hh, skips the 768 h@W_hh FMAs.
__device__ __forceinline__ void gru_step0(
    float x0, float x1,
    const float* __restrict__ w_ih, const float* __restrict__ b_ih,
    const float* __restrict__ b_hh, float (&h)[Hn])
{
#pragma unroll
    for (int j = 0; j < Hn; ++j) {
        const float ir  = fmaf(x1, w_ih[(j)      * 2 + 1], fmaf(x0, w_ih[(j)      * 2], b_ih[j]));
        const float iz  = fmaf(x1, w_ih[(16 + j) * 2 + 1], fmaf(x0, w_ih[(16 + j) * 2], b_ih[16 + j]));
        const float inn = fmaf(x1, w_ih[(32 + j) * 2 + 1], fmaf(x0, w_ih[(32 + j) * 2], b_ih[32 + j]));
        const float r = sigm_f(ir + b_hh[j]);
        const float z = sigm_f(iz + b_hh[16 + j]);
        const float n = tanh_f(fmaf(r, b_hh[32 + j], inn));
        h[j] = n - z * n;  // (1-z)*n + z*0
    }
}

// Full GRU step: hn = GRUCell(x, h).
__device__ __forceinline__ void gru_step(
    float x0, float x1,
    const float* __restrict__ w_ih, const float* __restrict__ w_hh,
    const float* __restrict__ b_ih, const float* __restrict__ b_hh,
    const float (&h)[Hn], float (&hn)[Hn])
{
#pragma unroll
    for (int j = 0; j < Hn; ++j) {
        const float ir  = fmaf(x1, w_ih[(j)      * 2 + 1], fmaf(x0, w_ih[(j)      * 2], b_ih[j]));
        const float iz  = fmaf(x1, w_ih[(16 + j) * 2 + 1], fmaf(x0, w_ih[(16 + j) * 2], b_ih[16 + j]));
        const float inn = fmaf(x1, w_ih[(32 + j) * 2 + 1], fmaf(x0, w_ih[(32 + j) * 2], b_ih[32 + j]));
        float hr = b_hh[j];
        float hz = b_hh[16 + j];
        float hg = b_hh[32 + j];
#pragma unroll
        for (int k = 0; k < Hn; ++k) {
            const float hk = h[k];
            hr = fmaf(hk, w_hh[(j)      * 16 + k], hr);
            hz = fmaf(hk, w_hh[(16 + j) * 16 + k], hz);
            hg = fmaf(hk, w_hh[(32 + j) * 16 + k], hg);
        }
        const float r = sigm_f(ir + hr);
        const float z = sigm_f(iz + hz);
        const float n = tanh_f(fmaf(r, hg, inn));
        hn[j] = fmaf(z, h[j] - n, n);  // (1-z)*n + z*h
    }
}

// 4-way-split dot product (breaks the 16-long serial FMA chain).
__device__ __forceinline__ float dot16_bias(
    const float (&h)[Hn], const float* __restrict__ w, float bias)
{
    float s0 = bias, s1 = 0.0f, s2 = 0.0f, s3 = 0.0f;
#pragma unroll
    for (int k = 0; k < Hn; k += 4) {
        s0 = fmaf(h[k + 0], w[k + 0], s0);
        s1 = fmaf(h[k + 1], w[k + 1], s1);
        s2 = fmaf(h[k + 2], w[k + 2], s2);
        s3 = fmaf(h[k + 3], w[k + 3], s3);
    }
    return (s0 + s1) + (s2 + s3);
}

__device__ __forceinline__ void store_h16(float* __restrict__ dst, const float (&h)[Hn])
{
    float4* hp = (float4*)dst;
    hp[0] = make_float4(h[0],  h[1],  h[2],  h[3]);
    hp[1] = make_float4(h[4],  h[5],  h[6],  h[7]);
    hp[2] = make_float4(h[8],  h[9],  h[10], h[11]);
    hp[3] = make_float4(h[12], h[13], h[14], h[15]);
}

__global__ __launch_bounds__(256, 4) void gru_adder_kernel(
    const float* __restrict__ x_bits,   // [B, 4, 2]
    const float* __restrict__ w_ih,     // [48, 2]
    const float* __restrict__ w_hh,     // [48, 16]
    const float* __restrict__ b_ih,     // [48]
    const float* __restrict__ b_hh,     // [48]
    const float* __restrict__ w_sum,    // [1, 16]
    const float* __restrict__ b_sum,    // [1]
    const float* __restrict__ w_carry,  // [1, 16]
    const float* __restrict__ b_carry,  // [1]
    float* __restrict__ out)            // [64B | 4B | B | 5B] floats
{
    const long long g  = (long long)blockIdx.x * blockDim.x + threadIdx.x;
    const long long b0 = 2 * g;  // this thread handles batch b0 and b0+1

    // 16 consecutive x floats (both elements' full sequences): 64B/lane, coalesced.
    const float4* xp = (const float4*)(x_bits + b0 * 8);
    const float4 v0 = xp[0], v1 = xp[1];  // element A: t0..t3
    const float4 v2 = xp[2], v3 = xp[3];  // element B: t0..t3

    float ha[Hn], hb[Hn];

    // ---- t = 0 (h == 0 specialization) ----
    gru_step0(v0.x, v0.y, w_ih, b_ih, b_hh, ha);
    gru_step0(v2.x, v2.y, w_ih, b_ih, b_hh, hb);

    store_h16(out + (b0 * 4 + 0) * 16, ha);
    store_h16(out + ((b0 + 1) * 4 + 0) * 16, hb);
    {
        const float bs = b_sum[0];
        const float sa = dot16_bias(ha, w_sum, bs);
        const float sb = dot16_bias(hb, w_sum, bs);
        out[64ll * Bn + b0 * 4 + 0]     = sa;
        out[64ll * Bn + b0 * 4 + 4]     = sb;
        out[69ll * Bn + b0 * 5 + 0]     = sa;
        out[69ll * Bn + b0 * 5 + 5]     = sb;
    }

    // x shift-register queues (no runtime-indexed arrays -> stays in VGPRs).
    float qa0 = v0.z, qa1 = v0.w, qa2 = v1.x, qa3 = v1.y, qa4 = v1.z, qa5 = v1.w;
    float qb0 = v2.z, qb1 = v2.w, qb2 = v3.x, qb3 = v3.y, qb4 = v3.z, qb5 = v3.w;

    // ---- t = 1..3, ROLLED: ~half the code footprint, 3x I$ reuse ----
#pragma unroll 1
    for (int t = 1; t < 4; ++t) {
        float hna[Hn], hnb[Hn];
        gru_step(qa0, qa1, w_ih, w_hh, b_ih, b_hh, ha, hna);
        gru_step(qb0, qb1, w_ih, w_hh, b_ih, b_hh, hb, hnb);
#pragma unroll
        for (int j = 0; j < Hn; ++j) { ha[j] = hna[j]; hb[j] = hnb[j]; }
        // advance x queues
        qa0 = qa2; qa1 = qa3; qa2 = qa4; qa3 = qa5;
        qb0 = qb2; qb1 = qb3; qb2 = qb4; qb3 = qb5;

        store_h16(out + (b0 * 4 + t) * 16, ha);
        store_h16(out + ((b0 + 1) * 4 + t) * 16, hb);

        const float bs = b_sum[0];
        const float sa = dot16_bias(ha, w_sum, bs);
        const float sb = dot16_bias(hb, w_sum, bs);
        out[64ll * Bn + b0 * 4 + t]     = sa;
        out[64ll * Bn + b0 * 4 + 4 + t] = sb;
        out[69ll * Bn + b0 * 5 + t]     = sa;
        out[69ll * Bn + b0 * 5 + 5 + t] = sb;
    }

    // ---- carry logits from final h ----
    const float bc = b_carry[0];
    const float ca = dot16_bias(ha, w_carry, bc);
    const float cb = dot16_bias(hb, w_carry, bc);
    *(float2*)(out + 68ll * Bn + b0) = make_float2(ca, cb);
    out[69ll * Bn + b0 * 5 + 4] = ca;
    out[69ll * Bn + b0 * 5 + 9] = cb;
}

extern "C" void kernel_launch(void* const* d_in, const int* in_sizes, int n_in,
                              void* d_out, int out_size, void* d_ws, size_t ws_size,
                              hipStream_t stream) {
    const float* x_bits  = (const float*)d_in[0];
    const float* w_ih    = (const float*)d_in[1];
    const float* w_hh    = (const float*)d_in[2];
    const float* b_ih    = (const float*)d_in[3];
    const float* b_hh    = (const float*)d_in[4];
    const float* w_sum   = (const float*)d_in[5];
    const float* b_sum   = (const float*)d_in[6];
    const float* w_carry = (const float*)d_in[7];
    const float* b_carry = (const float*)d_in[8];
    float* out = (float*)d_out;

    const int block = 256;
    const long long threads = Bn / 2;                    // 2 elements per thread
    const int grid = (int)((threads + block - 1) / block);  // 2048
    gru_adder_kernel<<<grid, block, 0, stream>>>(
        x_bits, w_ih, w_hh, b_ih, b_hh, w_sum, b_sum, w_carry, b_carry, out);
}